// Round 5
// baseline (939.621 us; speedup 1.0000x reference)
//
#include <hip/hip_runtime.h>

typedef _Float16 half_t;
typedef __attribute__((ext_vector_type(4))) _Float16 half4;
typedef __attribute__((ext_vector_type(8))) _Float16 half8;
typedef __attribute__((ext_vector_type(4))) float f32x4;

#define WS_W1   0                          // 768*256 fp16 = 393216 B
#define WS_W2   (768*256*2)                // 256*256 fp16 = 131072 B
#define WS_BIAS (WS_W2 + 256*256*2)        // 8*4096 fp32 (transposed-C-fragment permuted)
#define QK_SCALE 0.17677669529663687f      // 32^-0.5

// ---------------- prep: weight fp32->fp16 + rpb bias gather (permuted) ----------------
// BIASP layout matches the TRANSPOSED S tile (S^T = mfma(K,Q)):
// value at (h, it, jt, quad, l16, r) = bias[h][i = 16*it + l16][j = 16*jt + 4*quad + r]
__global__ __launch_bounds__(256) void prep_kernel(
    const float* __restrict__ qkv_w, const float* __restrict__ proj_w,
    const float* __restrict__ rpb, const int* __restrict__ rel_idx,
    char* __restrict__ ws) {
  int tid = blockIdx.x * 256 + threadIdx.x;
  half_t* W1 = (half_t*)(ws + WS_W1);
  half_t* W2 = (half_t*)(ws + WS_W2);
  float* BIASP = (float*)(ws + WS_BIAS);
  if (tid < 768 * 256) {
    int n = tid >> 8;
    float v = qkv_w[tid];
    if (n < 256) v *= QK_SCALE;          // fold q-scale into Wq
    W1[tid] = (half_t)v;
  }
  if (tid < 256 * 256) W2[tid] = (half_t)proj_w[tid];
  if (tid < 8 * 4096) {
    int r   = tid & 3;
    int l16 = (tid >> 2) & 15;
    int q   = (tid >> 6) & 3;
    int nt  = (tid >> 8) & 3;   // jt
    int mt  = (tid >> 10) & 3;  // it
    int h   = (tid >> 12) & 7;
    int i = 16 * mt + l16;       // query token
    int j = 16 * nt + 4 * q + r; // key token
    BIASP[tid] = rpb[rel_idx[i * 64 + j] * 8 + h];
  }
}

// QKV sub-GEMM: 64 tokens x 32 output dims (2 n-tiles), K=256.
__device__ __forceinline__ void qkv_gemm(const half_t* Xs, const half_t* W1,
                                         int n0, int l16, int quad,
                                         f32x4 acc[2][4]) {
#pragma unroll
  for (int ks = 0; ks < 8; ++ks) {
    half8 af[4];
#pragma unroll
    for (int mt = 0; mt < 4; ++mt)
      af[mt] = *(const half8*)(&Xs[(16 * mt + l16) * 264 + 32 * ks + quad * 8]);
#pragma unroll
    for (int nt = 0; nt < 2; ++nt) {
      half8 bf = *(const half8*)(&W1[(size_t)(n0 + 16 * nt + l16) * 256 + 32 * ks + quad * 8]);
#pragma unroll
      for (int mt = 0; mt < 4; ++mt)
        acc[nt][mt] = __builtin_amdgcn_mfma_f32_16x16x32_f16(af[mt], bf, acc[nt][mt], 0, 0, 0);
    }
  }
}

// ---------------- fused kernel: 256-thread blocks, 3 blocks/CU ----------------
// LDS: 33792 (Xs) + 18432 (Scr) = 52224 B -> 3 blocks/CU = 3 waves/SIMD
// -> 170-reg budget (~104 arch + 64 acc). This is the missing middle point:
// rounds 1-4 (128 budget -> 64 arch) spilled ~550 MB of scratch; round 0
// (256 budget) had only 2 waves/SIMD. Mask LDS is dropped; mask is read fp32
// directly from global (L2/L3-resident). Each wave owns heads {w, w+4}
// sequentially, with head_dim=32 keeping QK^T/softmax/PV fully in registers.
__global__ __attribute__((amdgpu_flat_work_group_size(256, 256),
                          amdgpu_waves_per_eu(3, 3))) void fused_kernel(
    const float* __restrict__ x, const float* __restrict__ mask,
    const float* __restrict__ qkv_b, const float* __restrict__ proj_b,
    const char* __restrict__ ws, float* __restrict__ out, int nW) {
  __shared__ __align__(16) half_t Xs[64 * 264];   // x fp16; reused as AO after barrier
  __shared__ __align__(16) half_t Scr[4][2304];   // per-wave scratch (Q then K, serially)

  const int b = blockIdx.x;
  const int tid = threadIdx.x;
  const int wave = tid >> 6, lane = tid & 63;
  const int l16 = lane & 15, quad = lane >> 4;
  const f32x4 z4 = {0.f, 0.f, 0.f, 0.f};
  const half_t* W1 = (const half_t*)(ws + WS_W1);
  half_t* Sw = &Scr[wave][0];

  // ---- phase 0: stage x (fp32->fp16) into LDS, coalesced float4 ----
  {
    const float4* xw = (const float4*)(x + (size_t)b * 16384);
#pragma unroll
    for (int i = 0; i < 16; ++i) {
      int idx4 = tid + i * 256;
      float4 v = xw[idx4];
      int e = idx4 << 2;
      int row = e >> 8, col = e & 255;
      half4 pk;
      pk[0] = (half_t)v.x; pk[1] = (half_t)v.y; pk[2] = (half_t)v.z; pk[3] = (half_t)v.w;
      *(half4*)(&Xs[row * 264 + col]) = pk;
    }
  }
  __syncthreads();

  const float* Mw = mask + (size_t)(b % nW) * 4096;
  const float4* BP4 = (const float4*)(ws + WS_BIAS);
  half4 oh[2][4][2];       // normalized O^T fragments for both heads (fp16, 16 regs)

#pragma unroll
  for (int hh = 0; hh < 2; ++hh) {
    const int h = wave + 4 * hh;
    half4 vh[2][4];        // V^T A-fragments (K=16), built in-register from V-gemm acc
    half8 qf[4];           // Q B-fragments (token-major, d-slice)
    half8 kf[4];           // K A-fragments (token-major, d-slice)

    // ---- V pass: V = X @ Wv^T + b; C-layout IS the 16x16x16 A-frag of V^T ----
    {
      f32x4 acc[2][4];
#pragma unroll
      for (int nt = 0; nt < 2; ++nt)
#pragma unroll
        for (int mt = 0; mt < 4; ++mt) acc[nt][mt] = z4;
      const int n0 = 512 + 32 * h;
      qkv_gemm(Xs, W1, n0, l16, quad, acc);
#pragma unroll
      for (int nt = 0; nt < 2; ++nt) {
        float vb = qkv_b[n0 + 16 * nt + l16];
#pragma unroll
        for (int mt = 0; mt < 4; ++mt)
#pragma unroll
          for (int r = 0; r < 4; ++r)
            vh[nt][mt][r] = (half_t)(acc[nt][mt][r] + vb);
      }
    }

    // ---- Q pass: stage [t][d] stride 36 (conflict-free writes) -> qf ----
    {
      f32x4 acc[2][4];
#pragma unroll
      for (int nt = 0; nt < 2; ++nt)
#pragma unroll
        for (int mt = 0; mt < 4; ++mt) acc[nt][mt] = z4;
      const int n0 = 32 * h;
      qkv_gemm(Xs, W1, n0, l16, quad, acc);
#pragma unroll
      for (int nt = 0; nt < 2; ++nt) {
        float qb = qkv_b[n0 + 16 * nt + l16] * QK_SCALE;
#pragma unroll
        for (int mt = 0; mt < 4; ++mt)
#pragma unroll
          for (int r = 0; r < 4; ++r)
            Sw[(16 * mt + 4 * quad + r) * 36 + 16 * nt + l16] = (half_t)(acc[nt][mt][r] + qb);
      }
#pragma unroll
      for (int mt = 0; mt < 4; ++mt) {
        union { half8 v; half4 hh2[2]; } u;
        u.hh2[0] = *(const half4*)(&Sw[(16 * mt + l16) * 36 + quad * 8]);
        u.hh2[1] = *(const half4*)(&Sw[(16 * mt + l16) * 36 + quad * 8 + 4]);
        qf[mt] = u.v;
      }
      asm volatile("s_waitcnt lgkmcnt(0)" ::: "memory");  // qf landed before K overwrites
    }

    // ---- K pass: stage -> kf[0..3] ----
    {
      f32x4 acc[2][4];
#pragma unroll
      for (int nt = 0; nt < 2; ++nt)
#pragma unroll
        for (int mt = 0; mt < 4; ++mt) acc[nt][mt] = z4;
      const int n0 = 256 + 32 * h;
      qkv_gemm(Xs, W1, n0, l16, quad, acc);
#pragma unroll
      for (int nt = 0; nt < 2; ++nt) {
        float kb = qkv_b[n0 + 16 * nt + l16];
#pragma unroll
        for (int mt = 0; mt < 4; ++mt)
#pragma unroll
          for (int r = 0; r < 4; ++r)
            Sw[(16 * mt + 4 * quad + r) * 36 + 16 * nt + l16] = (half_t)(acc[nt][mt][r] + kb);
      }
#pragma unroll
      for (int jt = 0; jt < 4; ++jt) {
        union { half8 v; half4 hh2[2]; } u;
        u.hh2[0] = *(const half4*)(&Sw[(16 * jt + l16) * 36 + quad * 8]);
        u.hh2[1] = *(const half4*)(&Sw[(16 * jt + l16) * 36 + quad * 8 + 4]);
        kf[jt] = u.v;
      }
      asm volatile("s_waitcnt lgkmcnt(0)" ::: "memory");  // kf landed before next Scr write
    }

    // ---- attention: S^T per it-tile, softmax fully in-register, PV via 16x16x16 ----
#pragma unroll
    for (int it = 0; it < 4; ++it) {
      // S^T[jt] = mfma(K,Q): lane (l16,quad) holds S[i=16it+l16][j=16jt+4quad+r]
      f32x4 Sj[4];
#pragma unroll
      for (int jt = 0; jt < 4; ++jt)
        Sj[jt] = __builtin_amdgcn_mfma_f32_16x16x32_f16(kf[jt], qf[it], z4, 0, 0, 0);
#pragma unroll
      for (int jt = 0; jt < 4; ++jt) {
        float4 bv = BP4[(size_t)(((h * 4 + it) * 4 + jt) * 64) + quad * 16 + l16];
        float4 mv = *(const float4*)(&Mw[(16 * it + l16) * 64 + 16 * jt + 4 * quad]);
#pragma unroll
        for (int r = 0; r < 4; ++r)
          Sj[jt][r] += ((const float*)&bv)[r] + ((const float*)&mv)[r];
      }
      // row i = 16it+l16: 16 lane-local values + the 3 sibling quads
      float mx = Sj[0][0];
#pragma unroll
      for (int jt = 0; jt < 4; ++jt)
#pragma unroll
        for (int r = 0; r < 4; ++r) mx = fmaxf(mx, Sj[jt][r]);
      mx = fmaxf(mx, __shfl_xor(mx, 16, 64));
      mx = fmaxf(mx, __shfl_xor(mx, 32, 64));
      float s = 0.f;
      half4 ph[4];         // PV B-fragment = exp(S^T) in-lane, no LDS round-trip
#pragma unroll
      for (int jt = 0; jt < 4; ++jt)
#pragma unroll
        for (int r = 0; r < 4; ++r) {
          float e = exp2f((Sj[jt][r] - mx) * 1.44269504f);
          s += e;
          ph[jt][r] = (half_t)e;
        }
      s += __shfl_xor(s, 16, 64);
      s += __shfl_xor(s, 32, 64);
      float linv = __builtin_amdgcn_rcpf(s);  // normalize O after PV
      f32x4 o0 = z4, o1 = z4;
#pragma unroll
      for (int jt = 0; jt < 4; ++jt) {
        o0 = __builtin_amdgcn_mfma_f32_16x16x16f16(vh[0][jt], ph[jt], o0, 0, 0, 0);
        o1 = __builtin_amdgcn_mfma_f32_16x16x16f16(vh[1][jt], ph[jt], o1, 0, 0, 0);
      }
#pragma unroll
      for (int r = 0; r < 4; ++r) {
        oh[hh][it][0][r] = (half_t)(o0[r] * linv);
        oh[hh][it][1][r] = (half_t)(o1[r] * linv);
      }
    }
  }
  __syncthreads();

  // ---- AO exchange: O^T frags -> Xs (token-row major, head h -> cols [32h,32h+32)) ----
#pragma unroll
  for (int hh = 0; hh < 2; ++hh)
#pragma unroll
    for (int it = 0; it < 4; ++it)
#pragma unroll
      for (int dt = 0; dt < 2; ++dt)
        *(half4*)(&Xs[(16 * it + l16) * 264 + 32 * (wave + 4 * hh) + 16 * dt + 4 * quad]) =
            oh[hh][it][dt];
  __syncthreads();

  // ---- proj: out = AO[64x256] @ W2^T + b ; wave w -> out-dims [64w, 64w+64) ----
  {
    const half_t* W2 = (const half_t*)(ws + WS_W2);
    const int nb = wave * 64;
    f32x4 C[4][4];
#pragma unroll
    for (int nt = 0; nt < 4; ++nt)
#pragma unroll
      for (int mt = 0; mt < 4; ++mt) C[nt][mt] = z4;
#pragma unroll
    for (int ks = 0; ks < 8; ++ks) {
      half8 af[4];
#pragma unroll
      for (int mt = 0; mt < 4; ++mt)
        af[mt] = *(const half8*)(&Xs[(16 * mt + l16) * 264 + 32 * ks + quad * 8]);
#pragma unroll
      for (int nt = 0; nt < 4; ++nt) {
        half8 bf = *(const half8*)(&W2[(size_t)(nb + 16 * nt + l16) * 256 + 32 * ks + quad * 8]);
#pragma unroll
        for (int mt = 0; mt < 4; ++mt)
          C[nt][mt] = __builtin_amdgcn_mfma_f32_16x16x32_f16(af[mt], bf, C[nt][mt], 0, 0, 0);
      }
    }
#pragma unroll
    for (int nt = 0; nt < 4; ++nt) {
      int c = nb + 16 * nt + l16;
      float pb = proj_b[c];
#pragma unroll
      for (int mt = 0; mt < 4; ++mt)
#pragma unroll
        for (int r = 0; r < 4; ++r) {
          int t = 16 * mt + 4 * quad + r;
          out[(size_t)b * 16384 + t * 256 + c] = C[nt][mt][r] + pb;
        }
    }
  }
}

extern "C" void kernel_launch(void* const* d_in, const int* in_sizes, int n_in,
                              void* d_out, int out_size, void* d_ws, size_t ws_size,
                              hipStream_t stream) {
  const float* x      = (const float*)d_in[0];
  const float* mask   = (const float*)d_in[1];
  const float* rpb    = (const float*)d_in[2];
  const float* qkv_w  = (const float*)d_in[3];
  const float* qkv_b  = (const float*)d_in[4];
  const float* proj_w = (const float*)d_in[5];
  const float* proj_b = (const float*)d_in[6];
  const int*   rel    = (const int*)d_in[7];
  float* out = (float*)d_out;
  char* ws = (char*)d_ws;
  int B_ = in_sizes[0] / 16384;   // windows*batch
  int nW = in_sizes[1] / 4096;    // mask windows
  hipLaunchKernelGGL(prep_kernel, dim3(768), dim3(256), 0, stream,
                     qkv_w, proj_w, rpb, rel, ws);
  hipLaunchKernelGGL(fused_kernel, dim3(B_), dim3(256), 0, stream,
                     x, mask, qkv_b, proj_b, (const char*)ws, out, nW);
}

// Round 6
// 783.962 us; speedup vs baseline: 1.1986x; 1.1986x over previous
//
#include <hip/hip_runtime.h>

typedef _Float16 half_t;
typedef __attribute__((ext_vector_type(4))) _Float16 half4;
typedef __attribute__((ext_vector_type(8))) _Float16 half8;
typedef __attribute__((ext_vector_type(4))) float f32x4;

#define WS_W1   0                          // 768*256 fp16 = 393216 B
#define WS_W2   (768*256*2)                // 256*256 fp16 = 131072 B
#define WS_BIAS (WS_W2 + 256*256*2)        // 8*4096 fp32 (transposed-C-fragment permuted)
#define QK_SCALE 0.17677669529663687f      // 32^-0.5

// ---------------- prep: weight fp32->fp16 + rpb bias gather (permuted) ----------------
// BIASP layout matches the TRANSPOSED S tile (S^T = mfma(K,Q)):
// value at (h, it, jt, quad, l16, r) = bias[h][i = 16*it + l16][j = 16*jt + 4*quad + r]
__global__ __launch_bounds__(256) void prep_kernel(
    const float* __restrict__ qkv_w, const float* __restrict__ proj_w,
    const float* __restrict__ rpb, const int* __restrict__ rel_idx,
    char* __restrict__ ws) {
  int tid = blockIdx.x * 256 + threadIdx.x;
  half_t* W1 = (half_t*)(ws + WS_W1);
  half_t* W2 = (half_t*)(ws + WS_W2);
  float* BIASP = (float*)(ws + WS_BIAS);
  if (tid < 768 * 256) {
    int n = tid >> 8;
    float v = qkv_w[tid];
    if (n < 256) v *= QK_SCALE;          // fold q-scale into Wq
    W1[tid] = (half_t)v;
  }
  if (tid < 256 * 256) W2[tid] = (half_t)proj_w[tid];
  if (tid < 8 * 4096) {
    int r   = tid & 3;
    int l16 = (tid >> 2) & 15;
    int q   = (tid >> 6) & 3;
    int nt  = (tid >> 8) & 3;   // jt
    int mt  = (tid >> 10) & 3;  // it
    int h   = (tid >> 12) & 7;
    int i = 16 * mt + l16;       // query token
    int j = 16 * nt + 4 * q + r; // key token
    BIASP[tid] = rpb[rel_idx[i * 64 + j] * 8 + h];
  }
}

// QKV sub-GEMM: 64 tokens x 32 output dims (2 n-tiles), K=256.
__device__ __forceinline__ void qkv_gemm(const half_t* Xs, const half_t* W1,
                                         int n0, int l16, int quad,
                                         f32x4 acc[2][4]) {
#pragma unroll
  for (int ks = 0; ks < 8; ++ks) {
    half8 af[4];
#pragma unroll
    for (int mt = 0; mt < 4; ++mt)
      af[mt] = *(const half8*)(&Xs[(16 * mt + l16) * 264 + 32 * ks + quad * 8]);
#pragma unroll
    for (int nt = 0; nt < 2; ++nt) {
      half8 bf = *(const half8*)(&W1[(size_t)(n0 + 16 * nt + l16) * 256 + 32 * ks + quad * 8]);
#pragma unroll
      for (int mt = 0; mt < 4; ++mt)
        acc[nt][mt] = __builtin_amdgcn_mfma_f32_16x16x32_f16(af[mt], bf, acc[nt][mt], 0, 0, 0);
    }
  }
}

// ---------------- fused kernel: lean per-head dataflow, NO-SPILL budget ----------------
// LDS: 33792 (Xs) + 36864 (Scr) = 70656 B.
// __launch_bounds__(512, 2): 256-reg budget -- the only setting measured spill-free
// (round 0: VGPR 96, WRITE == output). Rounds 1-5 proved every <256 budget spills
// 400-550 B/thread (~0.5 GB HBM writeback). This round isolates spill removal on
// the lean round-4 algorithm and measures its true register demand.
// Wave h owns head h; head_dim=32 keeps QK^T/softmax/PV fully in registers:
//  - V-gemm accumulators convert in-register into V^T A-frags (16x16x16 PV),
//  - S^T = mfma(K,Q) puts P-rows in-lane: softmax = 2 shuffles, exp -> PV B-frag.
// Mask is read fp32 from global (stream-once, L2-friendly); no Ms staging.
__global__ __launch_bounds__(512, 2) void fused_kernel(
    const float* __restrict__ x, const float* __restrict__ mask,
    const float* __restrict__ qkv_b, const float* __restrict__ proj_b,
    const char* __restrict__ ws, float* __restrict__ out, int nW) {
  __shared__ __align__(16) half_t Xs[64 * 264];   // x fp16; reused as AO after barrier
  __shared__ __align__(16) half_t Scr[8][2304];   // per-wave scratch (Q then K, serially)

  const int b = blockIdx.x;
  const int tid = threadIdx.x;
  const int wave = tid >> 6, lane = tid & 63;
  const int l16 = lane & 15, quad = lane >> 4;
  const f32x4 z4 = {0.f, 0.f, 0.f, 0.f};
  const half_t* W1 = (const half_t*)(ws + WS_W1);
  half_t* Sw = &Scr[wave][0];

  // ---- phase 0: stage x (fp32->fp16) into LDS, coalesced float4 ----
  {
    const float4* xw = (const float4*)(x + (size_t)b * 16384);
#pragma unroll
    for (int i = 0; i < 8; ++i) {
      int idx4 = tid + i * 512;
      float4 v = xw[idx4];
      int e = idx4 << 2;
      int row = e >> 8, col = e & 255;
      half4 pk;
      pk[0] = (half_t)v.x; pk[1] = (half_t)v.y; pk[2] = (half_t)v.z; pk[3] = (half_t)v.w;
      *(half4*)(&Xs[row * 264 + col]) = pk;
    }
  }
  __syncthreads();

  const int h = wave;
  const float* Mw = mask + (size_t)(b % nW) * 4096;
  const float4* BP4 = (const float4*)(ws + WS_BIAS);
  half4 vh[2][4];          // V^T A-fragments (K=16), built in-register from V-gemm acc
  half8 qf[4];             // Q B-fragments (token-major, d-slice)
  half8 kf[4];             // K A-fragments (token-major, d-slice)
  half4 oh[4][2];          // normalized O^T fragments (fp16)

  // ---- V pass: V = X @ Wv^T + b; C-layout IS the 16x16x16 A-frag of V^T ----
  {
    f32x4 acc[2][4];
#pragma unroll
    for (int nt = 0; nt < 2; ++nt)
#pragma unroll
      for (int mt = 0; mt < 4; ++mt) acc[nt][mt] = z4;
    const int n0 = 512 + 32 * h;
    qkv_gemm(Xs, W1, n0, l16, quad, acc);
#pragma unroll
    for (int nt = 0; nt < 2; ++nt) {
      float vb = qkv_b[n0 + 16 * nt + l16];
#pragma unroll
      for (int mt = 0; mt < 4; ++mt)
#pragma unroll
        for (int r = 0; r < 4; ++r)
          vh[nt][mt][r] = (half_t)(acc[nt][mt][r] + vb);
    }
  }

  // ---- Q pass: stage [t][d] stride 36 (conflict-free writes) -> qf ----
  {
    f32x4 acc[2][4];
#pragma unroll
    for (int nt = 0; nt < 2; ++nt)
#pragma unroll
      for (int mt = 0; mt < 4; ++mt) acc[nt][mt] = z4;
    const int n0 = 32 * h;
    qkv_gemm(Xs, W1, n0, l16, quad, acc);
#pragma unroll
    for (int nt = 0; nt < 2; ++nt) {
      float qb = qkv_b[n0 + 16 * nt + l16] * QK_SCALE;
#pragma unroll
      for (int mt = 0; mt < 4; ++mt)
#pragma unroll
        for (int r = 0; r < 4; ++r)
          Sw[(16 * mt + 4 * quad + r) * 36 + 16 * nt + l16] = (half_t)(acc[nt][mt][r] + qb);
    }
#pragma unroll
    for (int mt = 0; mt < 4; ++mt) {
      union { half8 v; half4 hh[2]; } u;
      u.hh[0] = *(const half4*)(&Sw[(16 * mt + l16) * 36 + quad * 8]);
      u.hh[1] = *(const half4*)(&Sw[(16 * mt + l16) * 36 + quad * 8 + 4]);
      qf[mt] = u.v;
    }
    asm volatile("s_waitcnt lgkmcnt(0)" ::: "memory");  // qf landed before K overwrites
  }

  // ---- K pass: stage -> kf[0..3] ----
  {
    f32x4 acc[2][4];
#pragma unroll
    for (int nt = 0; nt < 2; ++nt)
#pragma unroll
      for (int mt = 0; mt < 4; ++mt) acc[nt][mt] = z4;
    const int n0 = 256 + 32 * h;
    qkv_gemm(Xs, W1, n0, l16, quad, acc);
#pragma unroll
    for (int nt = 0; nt < 2; ++nt) {
      float kb = qkv_b[n0 + 16 * nt + l16];
#pragma unroll
      for (int mt = 0; mt < 4; ++mt)
#pragma unroll
        for (int r = 0; r < 4; ++r)
          Sw[(16 * mt + 4 * quad + r) * 36 + 16 * nt + l16] = (half_t)(acc[nt][mt][r] + kb);
    }
#pragma unroll
    for (int jt = 0; jt < 4; ++jt) {
      union { half8 v; half4 hh[2]; } u;
      u.hh[0] = *(const half4*)(&Sw[(16 * jt + l16) * 36 + quad * 8]);
      u.hh[1] = *(const half4*)(&Sw[(16 * jt + l16) * 36 + quad * 8 + 4]);
      kf[jt] = u.v;
    }
  }

  // ---- attention: S^T per it-tile, softmax fully in-register, PV via 16x16x16 ----
#pragma unroll
  for (int it = 0; it < 4; ++it) {
    // S^T[jt] = mfma(K,Q): lane (l16,quad) holds S[i=16it+l16][j=16jt+4quad+r]
    f32x4 Sj[4];
#pragma unroll
    for (int jt = 0; jt < 4; ++jt)
      Sj[jt] = __builtin_amdgcn_mfma_f32_16x16x32_f16(kf[jt], qf[it], z4, 0, 0, 0);
#pragma unroll
    for (int jt = 0; jt < 4; ++jt) {
      float4 bv = BP4[(size_t)(((h * 4 + it) * 4 + jt) * 64) + quad * 16 + l16];
      float4 mv = *(const float4*)(&Mw[(16 * it + l16) * 64 + 16 * jt + 4 * quad]);
#pragma unroll
      for (int r = 0; r < 4; ++r)
        Sj[jt][r] += ((const float*)&bv)[r] + ((const float*)&mv)[r];
    }
    // row i = 16it+l16: 16 lane-local values + the 3 sibling quads
    float mx = Sj[0][0];
#pragma unroll
    for (int jt = 0; jt < 4; ++jt)
#pragma unroll
      for (int r = 0; r < 4; ++r) mx = fmaxf(mx, Sj[jt][r]);
    mx = fmaxf(mx, __shfl_xor(mx, 16, 64));
    mx = fmaxf(mx, __shfl_xor(mx, 32, 64));
    float s = 0.f;
    half4 ph[4];         // PV B-fragment = exp(S^T) in-lane, no LDS round-trip
#pragma unroll
    for (int jt = 0; jt < 4; ++jt)
#pragma unroll
      for (int r = 0; r < 4; ++r) {
        float e = exp2f((Sj[jt][r] - mx) * 1.44269504f);
        s += e;
        ph[jt][r] = (half_t)e;
      }
    s += __shfl_xor(s, 16, 64);
    s += __shfl_xor(s, 32, 64);
    float linv = __builtin_amdgcn_rcpf(s);  // normalize O after PV
    f32x4 o0 = z4, o1 = z4;
#pragma unroll
    for (int jt = 0; jt < 4; ++jt) {
      o0 = __builtin_amdgcn_mfma_f32_16x16x16f16(vh[0][jt], ph[jt], o0, 0, 0, 0);
      o1 = __builtin_amdgcn_mfma_f32_16x16x16f16(vh[1][jt], ph[jt], o1, 0, 0, 0);
    }
#pragma unroll
    for (int r = 0; r < 4; ++r) {
      oh[it][0][r] = (half_t)(o0[r] * linv);
      oh[it][1][r] = (half_t)(o1[r] * linv);
    }
  }
  __syncthreads();

  // ---- AO exchange: O^T frags -> Xs (token-row major, head h -> cols [32h,32h+32)) ----
#pragma unroll
  for (int it = 0; it < 4; ++it)
#pragma unroll
    for (int dt = 0; dt < 2; ++dt)
      *(half4*)(&Xs[(16 * it + l16) * 264 + 32 * h + 16 * dt + 4 * quad]) = oh[it][dt];
  __syncthreads();

  // ---- proj: out = AO[64x256] @ W2^T + b ; wave w -> out-dims [32w, 32w+32) ----
  {
    const half_t* W2 = (const half_t*)(ws + WS_W2);
    const int nb = wave * 32;
    f32x4 C[2][4];
#pragma unroll
    for (int nt = 0; nt < 2; ++nt)
#pragma unroll
      for (int mt = 0; mt < 4; ++mt) C[nt][mt] = z4;
#pragma unroll
    for (int ks = 0; ks < 8; ++ks) {
      half8 af[4];
#pragma unroll
      for (int mt = 0; mt < 4; ++mt)
        af[mt] = *(const half8*)(&Xs[(16 * mt + l16) * 264 + 32 * ks + quad * 8]);
#pragma unroll
      for (int nt = 0; nt < 2; ++nt) {
        half8 bf = *(const half8*)(&W2[(size_t)(nb + 16 * nt + l16) * 256 + 32 * ks + quad * 8]);
#pragma unroll
        for (int mt = 0; mt < 4; ++mt)
          C[nt][mt] = __builtin_amdgcn_mfma_f32_16x16x32_f16(af[mt], bf, C[nt][mt], 0, 0, 0);
      }
    }
#pragma unroll
    for (int nt = 0; nt < 2; ++nt) {
      int c = nb + 16 * nt + l16;
      float pb = proj_b[c];
#pragma unroll
      for (int mt = 0; mt < 4; ++mt)
#pragma unroll
        for (int r = 0; r < 4; ++r) {
          int t = 16 * mt + 4 * quad + r;
          out[(size_t)b * 16384 + t * 256 + c] = C[nt][mt][r] + pb;
        }
    }
  }
}

extern "C" void kernel_launch(void* const* d_in, const int* in_sizes, int n_in,
                              void* d_out, int out_size, void* d_ws, size_t ws_size,
                              hipStream_t stream) {
  const float* x      = (const float*)d_in[0];
  const float* mask   = (const float*)d_in[1];
  const float* rpb    = (const float*)d_in[2];
  const float* qkv_w  = (const float*)d_in[3];
  const float* qkv_b  = (const float*)d_in[4];
  const float* proj_w = (const float*)d_in[5];
  const float* proj_b = (const float*)d_in[6];
  const int*   rel    = (const int*)d_in[7];
  float* out = (float*)d_out;
  char* ws = (char*)d_ws;
  int B_ = in_sizes[0] / 16384;   // windows*batch
  int nW = in_sizes[1] / 4096;    // mask windows
  hipLaunchKernelGGL(prep_kernel, dim3(768), dim3(256), 0, stream,
                     qkv_w, proj_w, rpb, rel, ws);
  hipLaunchKernelGGL(fused_kernel, dim3(B_), dim3(512), 0, stream,
                     x, mask, qkv_b, proj_b, (const char*)ws, out, nW);
}